// Round 1
// baseline (2899.130 us; speedup 1.0000x reference)
//
#include <hip/hip_runtime.h>
#include <cstdint>
#include <cstddef>

// Sinkhorn: B=64, P=1024, T=1024, 50 iterations.
// Strategy: precompute K=exp(-C/reg) as bf16 (128MB in d_ws) -> halves the
// per-pass streaming traffic vs fp32. 2 full-K passes per iteration
// (inherent Gauss-Seidel dependency), + final Ktu + final P.

#define DEVI static __device__ __forceinline__

DEVI float bf2f(unsigned short s) { return __uint_as_float(((unsigned)s) << 16); }
DEVI unsigned short f2bf(float f) {
    unsigned u = __float_as_uint(f);
    u += 0x7FFFu + ((u >> 16) & 1u);   // round-to-nearest-even; inputs are positive normals
    return (unsigned short)(u >> 16);
}

__global__ __launch_bounds__(256) void k_init(float* __restrict__ u, int n) {
    int i = blockIdx.x * 256 + threadIdx.x;
    if (i < n) u[i] = 1.0f;
}

__global__ __launch_bounds__(256) void k_exp(const float4* __restrict__ C4,
        const float* __restrict__ regp, ushort4* __restrict__ K4, int n4) {
    const float negi = -1.0f / regp[0];
    int i = blockIdx.x * 256 + threadIdx.x;
    const int stride = gridDim.x * 256;
    for (; i < n4; i += stride) {
        float4 c = C4[i];
        ushort4 k;
        k.x = f2bf(__expf(c.x * negi));
        k.y = f2bf(__expf(c.y * negi));
        k.z = f2bf(__expf(c.z * negi));
        k.w = f2bf(__expf(c.w * negi));
        K4[i] = k;
    }
}

// v[b,t] = tgt[b,t] / sum_p K[b,p,t]*u[b,p]
// grid (T/128, B), block 256: tt=tid&31 covers 128 t (4 each, ushort4),
// pg=tid>>5 splits p 8 ways; LDS reduce across pg.
template<bool USE_C>
__global__ __launch_bounds__(256) void k_ktu(const unsigned short* __restrict__ K,
        const float* __restrict__ C, const float* __restrict__ regp,
        const float* __restrict__ u, const float* __restrict__ tgt,
        float* __restrict__ v) {
    __shared__ float su[1024];
    __shared__ float4 red[256];
    const int b = blockIdx.y;
    const int t0 = blockIdx.x * 128;
    const int tid = threadIdx.x;
    ((float4*)su)[tid] = ((const float4*)(u + (b << 10)))[tid];
    __syncthreads();
    const int tt = tid & 31;
    const int pg = tid >> 5;
    const int t = t0 + tt * 4;
    float4 acc = make_float4(0.f, 0.f, 0.f, 0.f);
    if (!USE_C) {
        const unsigned short* Kp = K + (((size_t)b) << 20) + ((size_t)pg << 10) + t;
        #pragma unroll 4
        for (int p = pg; p < 1024; p += 8) {
            ushort4 k4 = *(const ushort4*)Kp;
            float up = su[p];
            acc.x += bf2f(k4.x) * up;
            acc.y += bf2f(k4.y) * up;
            acc.z += bf2f(k4.z) * up;
            acc.w += bf2f(k4.w) * up;
            Kp += (size_t)8 << 10;
        }
    } else {
        const float negi = -1.0f / regp[0];
        const float* Cp = C + (((size_t)b) << 20) + ((size_t)pg << 10) + t;
        #pragma unroll 4
        for (int p = pg; p < 1024; p += 8) {
            float4 c4 = *(const float4*)Cp;
            float up = su[p];
            acc.x += __expf(c4.x * negi) * up;
            acc.y += __expf(c4.y * negi) * up;
            acc.z += __expf(c4.z * negi) * up;
            acc.w += __expf(c4.w * negi) * up;
            Cp += (size_t)8 << 10;
        }
    }
    red[tid] = acc;
    __syncthreads();
    if (tid < 32) {
        float4 s = red[tid];
        #pragma unroll
        for (int g = 1; g < 8; ++g) {
            float4 r = red[tid + (g << 5)];
            s.x += r.x; s.y += r.y; s.z += r.z; s.w += r.w;
        }
        const int tw = t0 + tid * 4;
        const float4 tg = *(const float4*)(tgt + (b << 10) + tw);
        float4 vv = make_float4(tg.x / s.x, tg.y / s.y, tg.z / s.z, tg.w / s.w);
        *(float4*)(v + (b << 10) + tw) = vv;
    }
}

// u[b,p] = pred[b,p] / sum_t K[b,p,t]*v[b,t]
// block 256 = 4 waves; wave per row (b,p); v row staged in LDS (same b for
// all 4 rows since blocks-per-b = 256 divides evenly).
template<bool USE_C>
__global__ __launch_bounds__(256) void k_kv(const unsigned short* __restrict__ K,
        const float* __restrict__ C, const float* __restrict__ regp,
        const float* __restrict__ v, const float* __restrict__ pred,
        float* __restrict__ u) {
    __shared__ float sv[1024];
    const int tid = threadIdx.x;
    const int row0 = blockIdx.x << 2;
    const int b = row0 >> 10;
    ((float4*)sv)[tid] = ((const float4*)(v + (b << 10)))[tid];
    __syncthreads();
    const int w = tid >> 6, l = tid & 63;
    const size_t row = (size_t)row0 + w;
    float s = 0.f;
    if (!USE_C) {
        const unsigned short* Kr = K + (row << 10);
        #pragma unroll
        for (int i = 0; i < 4; ++i) {
            const int t = (i << 8) + (l << 2);
            ushort4 k4 = *(const ushort4*)(Kr + t);
            float4 vv = *(const float4*)(sv + t);
            s += bf2f(k4.x) * vv.x + bf2f(k4.y) * vv.y
               + bf2f(k4.z) * vv.z + bf2f(k4.w) * vv.w;
        }
    } else {
        const float negi = -1.0f / regp[0];
        const float* Cr = C + (row << 10);
        #pragma unroll
        for (int i = 0; i < 4; ++i) {
            const int t = (i << 8) + (l << 2);
            float4 c4 = *(const float4*)(Cr + t);
            float4 vv = *(const float4*)(sv + t);
            s += __expf(c4.x * negi) * vv.x + __expf(c4.y * negi) * vv.y
               + __expf(c4.z * negi) * vv.z + __expf(c4.w * negi) * vv.w;
        }
    }
    #pragma unroll
    for (int m = 32; m >= 1; m >>= 1) s += __shfl_xor(s, m, 64);
    if (l == 0) u[row] = pred[row] / s;
}

// P[b,p,t] = u[b,p] * K[b,p,t] * v[b,t]; one block per row, float4 stores.
template<bool USE_C>
__global__ __launch_bounds__(256) void k_pout(const unsigned short* __restrict__ K,
        const float* __restrict__ C, const float* __restrict__ regp,
        const float* __restrict__ u, const float* __restrict__ v,
        float* __restrict__ out) {
    const size_t row = blockIdx.x;
    const int b = (int)(row >> 10);
    const int t = threadIdx.x << 2;
    const float up = u[row];
    const float4 vv = *(const float4*)(v + (b << 10) + t);
    float4 o;
    if (!USE_C) {
        ushort4 k4 = *(const ushort4*)(K + (row << 10) + t);
        o = make_float4(up * bf2f(k4.x) * vv.x, up * bf2f(k4.y) * vv.y,
                        up * bf2f(k4.z) * vv.z, up * bf2f(k4.w) * vv.w);
    } else {
        const float negi = -1.0f / regp[0];
        float4 c4 = *(const float4*)(C + (row << 10) + t);
        o = make_float4(up * __expf(c4.x * negi) * vv.x, up * __expf(c4.y * negi) * vv.y,
                        up * __expf(c4.z * negi) * vv.z, up * __expf(c4.w * negi) * vv.w);
    }
    *(float4*)(out + (row << 10) + t) = o;
}

extern "C" void kernel_launch(void* const* d_in, const int* in_sizes, int n_in,
                              void* d_out, int out_size, void* d_ws, size_t ws_size,
                              hipStream_t stream) {
    const float* pred = (const float*)d_in[0];   // (64,1024)
    const float* tgt  = (const float*)d_in[1];   // (64,1024)
    const float* C    = (const float*)d_in[2];   // (64,1024,1024)
    const float* regp = (const float*)d_in[3];   // scalar
    float* out = (float*)d_out;

    const size_t kbytes = (size_t)64 * 1024 * 1024 * 2;   // 128 MB bf16 K
    char* ws = (char*)d_ws;
    const bool useK = ws_size >= kbytes + (1u << 20);
    unsigned short* K = (unsigned short*)ws;
    float* u = useK ? (float*)(ws + kbytes) : (float*)ws;
    float* v = u + 65536;

    const dim3 blk(256);
    const dim3 gt(8, 64);      // ktu: 512 blocks
    const dim3 gv(16384);      // kv: wave per row
    const dim3 gp(65536);      // pout: block per row

    k_init<<<dim3(256), blk, 0, stream>>>(u, 65536);

    if (useK) {
        k_exp<<<dim3(4096), blk, 0, stream>>>((const float4*)C, regp, (ushort4*)K,
                                              16 * 1024 * 1024);
        for (int it = 0; it < 50; ++it) {
            k_ktu<false><<<gt, blk, 0, stream>>>(K, C, regp, u, tgt, v);
            k_kv <false><<<gv, blk, 0, stream>>>(K, C, regp, v, pred, u);
        }
        k_ktu<false><<<gt, blk, 0, stream>>>(K, C, regp, u, tgt, v);
        k_pout<false><<<gp, blk, 0, stream>>>(K, C, regp, u, v, out);
    } else {
        // fallback: recompute exp(-C/reg) on the fly every pass (needs only ~512KB ws)
        for (int it = 0; it < 50; ++it) {
            k_ktu<true><<<gt, blk, 0, stream>>>(K, C, regp, u, tgt, v);
            k_kv <true><<<gv, blk, 0, stream>>>(K, C, regp, v, pred, u);
        }
        k_ktu<true><<<gt, blk, 0, stream>>>(K, C, regp, u, tgt, v);
        k_pout<true><<<gp, blk, 0, stream>>>(K, C, regp, u, v, out);
    }
}

// Round 2
// 1964.888 us; speedup vs baseline: 1.4755x; 1.4755x over previous
//
#include <hip/hip_runtime.h>
#include <cstdint>
#include <cstddef>

// Sinkhorn: B=64, P=1024, T=1024, 50 iterations.
// R2: iterations stream fp8-e4m3 K (64MB, scale 2^8 folded out), final
// v/P recomputed from bf16 K (128MB). Scale cancels in u exactly.

#define DEVI static __device__ __forceinline__

DEVI float bf2f(unsigned short s) { return __uint_as_float(((unsigned)s) << 16); }
DEVI unsigned short f2bf(float f) {
    unsigned u = __float_as_uint(f);
    u += 0x7FFFu + ((u >> 16) & 1u);   // RNE; inputs positive normals
    return (unsigned short)(u >> 16);
}
// fp8 e4m3 encode (sign=0). Input pre-scaled by 256: f in (0, 256].
DEVI unsigned char f2fp8(float f) {
    if (f >= 0.015625f) {                      // normal fp8
        unsigned u = __float_as_uint(f);
        u += 0x7FFFFu + ((u >> 20) & 1u);      // RNE into 3-bit mantissa
        int e = (int)(u >> 23) - 127;
        return (unsigned char)(((e + 7) << 3) | ((u >> 20) & 7u));
    } else {                                   // subnormal: round(f*512)
        int n = (int)(f * 512.0f + 0.5f);      // n==8 aliases to e=1,m=0: correct
        return (unsigned char)n;
    }
}
// raw decode: returns K * 2^-112 (sum later multiplied by 2^112 once)
DEVI float fp8raw(unsigned b) { return __uint_as_float((b & 0x7Fu) << 20); }
#define FP8_SCALE 0x1.0p112f

__global__ __launch_bounds__(256) void k_init(float* __restrict__ u, int n) {
    int i = blockIdx.x * 256 + threadIdx.x;
    if (i < n) u[i] = 1.0f;
}

// K16 = bf16(exp(-C/reg)); K8 = e4m3(256*exp(-C/reg))
__global__ __launch_bounds__(256) void k_exp8(const float4* __restrict__ C4,
        const float* __restrict__ regp, ushort4* __restrict__ K16,
        unsigned* __restrict__ K8, int n4) {
    const float negi = -1.0f / regp[0];
    int i = blockIdx.x * 256 + threadIdx.x;
    const int stride = gridDim.x * 256;
    for (; i < n4; i += stride) {
        float4 c = C4[i];
        float k0 = __expf(c.x * negi), k1 = __expf(c.y * negi);
        float k2 = __expf(c.z * negi), k3 = __expf(c.w * negi);
        ushort4 h;
        h.x = f2bf(k0); h.y = f2bf(k1); h.z = f2bf(k2); h.w = f2bf(k3);
        K16[i] = h;
        unsigned p = (unsigned)f2fp8(k0 * 256.f)
                   | ((unsigned)f2fp8(k1 * 256.f) << 8)
                   | ((unsigned)f2fp8(k2 * 256.f) << 16)
                   | ((unsigned)f2fp8(k3 * 256.f) << 24);
        K8[i] = p;
    }
}

// bf16 exp-only (fallback path)
__global__ __launch_bounds__(256) void k_exp(const float4* __restrict__ C4,
        const float* __restrict__ regp, ushort4* __restrict__ K4, int n4) {
    const float negi = -1.0f / regp[0];
    int i = blockIdx.x * 256 + threadIdx.x;
    const int stride = gridDim.x * 256;
    for (; i < n4; i += stride) {
        float4 c = C4[i];
        ushort4 k;
        k.x = f2bf(__expf(c.x * negi));
        k.y = f2bf(__expf(c.y * negi));
        k.z = f2bf(__expf(c.z * negi));
        k.w = f2bf(__expf(c.w * negi));
        K4[i] = k;
    }
}

// fp8: v[b,t] = tgt[b,t] / sum_p K[b,p,t]*u[b,p]
// grid (8, 64), block 256: tt=tid&15 -> 16 lanes x 8 t = 128 t per block;
// pg=tid>>4 -> 16 p-groups, LDS reduce.
__global__ __launch_bounds__(256) void k_ktu8(const unsigned char* __restrict__ K8,
        const float* __restrict__ u, const float* __restrict__ tgt,
        float* __restrict__ v) {
    __shared__ float su[1024];
    __shared__ float red[256 * 9];   // pad 8->9 to break bank stride
    const int b = blockIdx.y;
    const int t0 = blockIdx.x * 128;
    const int tid = threadIdx.x;
    ((float4*)su)[tid] = ((const float4*)(u + (b << 10)))[tid];
    __syncthreads();
    const int tt = tid & 15;
    const int pg = tid >> 4;
    const unsigned char* Kp = K8 + (((size_t)b) << 20) + ((size_t)pg << 10) + t0 + tt * 8;
    float acc[8] = {0.f, 0.f, 0.f, 0.f, 0.f, 0.f, 0.f, 0.f};
    #pragma unroll 8
    for (int p = pg; p < 1024; p += 16) {
        uint2 k = *(const uint2*)Kp;
        float up = su[p];
        acc[0] += fp8raw(k.x) * up;
        acc[1] += fp8raw(k.x >> 8) * up;
        acc[2] += fp8raw(k.x >> 16) * up;
        acc[3] += fp8raw(k.x >> 24) * up;
        acc[4] += fp8raw(k.y) * up;
        acc[5] += fp8raw(k.y >> 8) * up;
        acc[6] += fp8raw(k.y >> 16) * up;
        acc[7] += fp8raw(k.y >> 24) * up;
        Kp += (size_t)16 << 10;
    }
    #pragma unroll
    for (int j = 0; j < 8; ++j) red[tid * 9 + j] = acc[j];
    __syncthreads();
    if (tid < 128) {
        const int tt2 = tid & 15;
        const int jj = tid >> 4;    // 0..7
        float s = 0.f;
        #pragma unroll
        for (int g = 0; g < 16; ++g) s += red[(g * 16 + tt2) * 9 + jj];
        const int t = t0 + tt2 * 8 + jj;
        v[(b << 10) + t] = tgt[(b << 10) + t] / (s * FP8_SCALE);
    }
}

// fp8: u[b,p] = pred[b,p] / sum_t K[b,p,t]*v[b,t]
// block 256 = 4 waves, 16 rows/wave (v row held in 16 regs, zero re-read).
__global__ __launch_bounds__(256) void k_kv8(const unsigned char* __restrict__ K8,
        const float* __restrict__ v, const float* __restrict__ pred,
        float* __restrict__ u) {
    const int tid = threadIdx.x;
    const int w = tid >> 6, l = tid & 63;
    const int row0 = (blockIdx.x << 6) + (w << 4);
    const int b = blockIdx.x >> 4;            // 16 blocks per batch
    const float* vb = v + (b << 10);
    const float4 v0 = *(const float4*)(vb + (l << 4));
    const float4 v1 = *(const float4*)(vb + (l << 4) + 4);
    const float4 v2 = *(const float4*)(vb + (l << 4) + 8);
    const float4 v3 = *(const float4*)(vb + (l << 4) + 12);
    #pragma unroll 4
    for (int r = 0; r < 16; ++r) {
        const size_t row = (size_t)row0 + r;
        uint4 k = ((const uint4*)(K8 + (row << 10)))[l];
        float s = fp8raw(k.x) * v0.x + fp8raw(k.x >> 8) * v0.y
                + fp8raw(k.x >> 16) * v0.z + fp8raw(k.x >> 24) * v0.w
                + fp8raw(k.y) * v1.x + fp8raw(k.y >> 8) * v1.y
                + fp8raw(k.y >> 16) * v1.z + fp8raw(k.y >> 24) * v1.w
                + fp8raw(k.z) * v2.x + fp8raw(k.z >> 8) * v2.y
                + fp8raw(k.z >> 16) * v2.z + fp8raw(k.z >> 24) * v2.w
                + fp8raw(k.w) * v3.x + fp8raw(k.w >> 8) * v3.y
                + fp8raw(k.w >> 16) * v3.z + fp8raw(k.w >> 24) * v3.w;
        #pragma unroll
        for (int m = 32; m >= 1; m >>= 1) s += __shfl_xor(s, m, 64);
        if (l == 0) u[row] = pred[row] / (s * FP8_SCALE);
    }
}

// ---- bf16 kernels (final pass + fallback) ----
template<bool USE_C>
__global__ __launch_bounds__(256) void k_ktu(const unsigned short* __restrict__ K,
        const float* __restrict__ C, const float* __restrict__ regp,
        const float* __restrict__ u, const float* __restrict__ tgt,
        float* __restrict__ v) {
    __shared__ float su[1024];
    __shared__ float4 red[256];
    const int b = blockIdx.y;
    const int t0 = blockIdx.x * 128;
    const int tid = threadIdx.x;
    ((float4*)su)[tid] = ((const float4*)(u + (b << 10)))[tid];
    __syncthreads();
    const int tt = tid & 31;
    const int pg = tid >> 5;
    const int t = t0 + tt * 4;
    float4 acc = make_float4(0.f, 0.f, 0.f, 0.f);
    if (!USE_C) {
        const unsigned short* Kp = K + (((size_t)b) << 20) + ((size_t)pg << 10) + t;
        #pragma unroll 4
        for (int p = pg; p < 1024; p += 8) {
            ushort4 k4 = *(const ushort4*)Kp;
            float up = su[p];
            acc.x += bf2f(k4.x) * up;
            acc.y += bf2f(k4.y) * up;
            acc.z += bf2f(k4.z) * up;
            acc.w += bf2f(k4.w) * up;
            Kp += (size_t)8 << 10;
        }
    } else {
        const float negi = -1.0f / regp[0];
        const float* Cp = C + (((size_t)b) << 20) + ((size_t)pg << 10) + t;
        #pragma unroll 4
        for (int p = pg; p < 1024; p += 8) {
            float4 c4 = *(const float4*)Cp;
            float up = su[p];
            acc.x += __expf(c4.x * negi) * up;
            acc.y += __expf(c4.y * negi) * up;
            acc.z += __expf(c4.z * negi) * up;
            acc.w += __expf(c4.w * negi) * up;
            Cp += (size_t)8 << 10;
        }
    }
    red[tid] = acc;
    __syncthreads();
    if (tid < 32) {
        float4 s = red[tid];
        #pragma unroll
        for (int g = 1; g < 8; ++g) {
            float4 r = red[tid + (g << 5)];
            s.x += r.x; s.y += r.y; s.z += r.z; s.w += r.w;
        }
        const int tw = t0 + tid * 4;
        const float4 tg = *(const float4*)(tgt + (b << 10) + tw);
        float4 vv = make_float4(tg.x / s.x, tg.y / s.y, tg.z / s.z, tg.w / s.w);
        *(float4*)(v + (b << 10) + tw) = vv;
    }
}

template<bool USE_C>
__global__ __launch_bounds__(256) void k_kv(const unsigned short* __restrict__ K,
        const float* __restrict__ C, const float* __restrict__ regp,
        const float* __restrict__ v, const float* __restrict__ pred,
        float* __restrict__ u) {
    __shared__ float sv[1024];
    const int tid = threadIdx.x;
    const int row0 = blockIdx.x << 2;
    const int b = row0 >> 10;
    ((float4*)sv)[tid] = ((const float4*)(v + (b << 10)))[tid];
    __syncthreads();
    const int w = tid >> 6, l = tid & 63;
    const size_t row = (size_t)row0 + w;
    float s = 0.f;
    if (!USE_C) {
        const unsigned short* Kr = K + (row << 10);
        #pragma unroll
        for (int i = 0; i < 4; ++i) {
            const int t = (i << 8) + (l << 2);
            ushort4 k4 = *(const ushort4*)(Kr + t);
            float4 vv = *(const float4*)(sv + t);
            s += bf2f(k4.x) * vv.x + bf2f(k4.y) * vv.y
               + bf2f(k4.z) * vv.z + bf2f(k4.w) * vv.w;
        }
    } else {
        const float negi = -1.0f / regp[0];
        const float* Cr = C + (row << 10);
        #pragma unroll
        for (int i = 0; i < 4; ++i) {
            const int t = (i << 8) + (l << 2);
            float4 c4 = *(const float4*)(Cr + t);
            float4 vv = *(const float4*)(sv + t);
            s += __expf(c4.x * negi) * vv.x + __expf(c4.y * negi) * vv.y
               + __expf(c4.z * negi) * vv.z + __expf(c4.w * negi) * vv.w;
        }
    }
    #pragma unroll
    for (int m = 32; m >= 1; m >>= 1) s += __shfl_xor(s, m, 64);
    if (l == 0) u[row] = pred[row] / s;
}

template<bool USE_C>
__global__ __launch_bounds__(256) void k_pout(const unsigned short* __restrict__ K,
        const float* __restrict__ C, const float* __restrict__ regp,
        const float* __restrict__ u, const float* __restrict__ v,
        float* __restrict__ out) {
    const size_t row = blockIdx.x;
    const int b = (int)(row >> 10);
    const int t = threadIdx.x << 2;
    const float up = u[row];
    const float4 vv = *(const float4*)(v + (b << 10) + t);
    float4 o;
    if (!USE_C) {
        ushort4 k4 = *(const ushort4*)(K + (row << 10) + t);
        o = make_float4(up * bf2f(k4.x) * vv.x, up * bf2f(k4.y) * vv.y,
                        up * bf2f(k4.z) * vv.z, up * bf2f(k4.w) * vv.w);
    } else {
        const float negi = -1.0f / regp[0];
        float4 c4 = *(const float4*)(C + (row << 10) + t);
        o = make_float4(up * __expf(c4.x * negi) * vv.x, up * __expf(c4.y * negi) * vv.y,
                        up * __expf(c4.z * negi) * vv.z, up * __expf(c4.w * negi) * vv.w);
    }
    *(float4*)(out + (row << 10) + t) = o;
}

extern "C" void kernel_launch(void* const* d_in, const int* in_sizes, int n_in,
                              void* d_out, int out_size, void* d_ws, size_t ws_size,
                              hipStream_t stream) {
    const float* pred = (const float*)d_in[0];
    const float* tgt  = (const float*)d_in[1];
    const float* C    = (const float*)d_in[2];
    const float* regp = (const float*)d_in[3];
    float* out = (float*)d_out;

    const size_t k16b = (size_t)64 * 1024 * 1024 * 2;   // 128 MB bf16
    const size_t k8b  = (size_t)64 * 1024 * 1024;       //  64 MB fp8
    char* ws = (char*)d_ws;
    const bool useFP8 = ws_size >= k16b + k8b + (1u << 20);
    const bool useK16 = ws_size >= k16b + (1u << 20);
    unsigned short* K16 = (unsigned short*)ws;
    unsigned char* K8 = (unsigned char*)(ws + k16b);
    float* u;
    if (useFP8)      u = (float*)(ws + k16b + k8b);
    else if (useK16) u = (float*)(ws + k16b);
    else             u = (float*)ws;
    float* v = u + 65536;

    const dim3 blk(256);
    const dim3 gt(8, 64);
    const dim3 gv(16384);
    const dim3 gv8(1024);
    const dim3 gp(65536);

    k_init<<<dim3(256), blk, 0, stream>>>(u, 65536);

    if (useFP8) {
        k_exp8<<<dim3(4096), blk, 0, stream>>>((const float4*)C, regp,
                (ushort4*)K16, (unsigned*)K8, 16 * 1024 * 1024);
        for (int it = 0; it < 50; ++it) {
            k_ktu8<<<gt, blk, 0, stream>>>(K8, u, tgt, v);
            k_kv8<<<gv8, blk, 0, stream>>>(K8, v, pred, u);
        }
        k_ktu<false><<<gt, blk, 0, stream>>>(K16, C, regp, u, tgt, v);
        k_pout<false><<<gp, blk, 0, stream>>>(K16, C, regp, u, v, out);
    } else if (useK16) {
        k_exp<<<dim3(4096), blk, 0, stream>>>((const float4*)C, regp,
                (ushort4*)K16, 16 * 1024 * 1024);
        for (int it = 0; it < 50; ++it) {
            k_ktu<false><<<gt, blk, 0, stream>>>(K16, C, regp, u, tgt, v);
            k_kv <false><<<gv, blk, 0, stream>>>(K16, C, regp, v, pred, u);
        }
        k_ktu<false><<<gt, blk, 0, stream>>>(K16, C, regp, u, tgt, v);
        k_pout<false><<<gp, blk, 0, stream>>>(K16, C, regp, u, v, out);
    } else {
        for (int it = 0; it < 50; ++it) {
            k_ktu<true><<<gt, blk, 0, stream>>>(K16, C, regp, u, tgt, v);
            k_kv <true><<<gv, blk, 0, stream>>>(K16, C, regp, v, pred, u);
        }
        k_ktu<true><<<gt, blk, 0, stream>>>(K16, C, regp, u, tgt, v);
        k_pout<true><<<gp, blk, 0, stream>>>(K16, C, regp, u, v, out);
    }
}